// Round 4
// baseline (734.306 us; speedup 1.0000x reference)
//
#include <hip/hip_runtime.h>
#include <hip/hip_bf16.h>

typedef __bf16 bf16;
typedef bf16 bf16x8 __attribute__((ext_vector_type(8)));
typedef float f32x4 __attribute__((ext_vector_type(4)));

#define MFMA16(a, b, c) __builtin_amdgcn_mfma_f32_16x16x32_bf16((a), (b), (c), 0, 0, 0)
#define UNROLL _Pragma("unroll")

__device__ __forceinline__ float fast_rcp(float x) { return __builtin_amdgcn_rcpf(x); }
__device__ __forceinline__ float fast_rsq(float x) { return __builtin_amdgcn_rsqf(x); }
__device__ __forceinline__ float fast_tanh(float x) {
    float e = __expf(2.0f * x);
    return 1.0f - 2.0f * fast_rcp(e + 1.0f);
}
__device__ __forceinline__ float fast_sigmoid(float x) {
    return fast_rcp(1.0f + __expf(-x));
}

// non-temporal loads/stores: keep single-use streams out of L2/L3 so the
// node table stays cache-resident (round-3 evidence: stream pollution
// caused ~400MB of gather re-fetch from a 12.8MB table)
__device__ __forceinline__ f32x4 ldnt4(const float* __restrict__ p) {
    return __builtin_nontemporal_load((const f32x4*)p);
}
__device__ __forceinline__ int ldnti(const int* __restrict__ p) {
    return __builtin_nontemporal_load(p);
}
__device__ __forceinline__ void stnt4(float* __restrict__ p, f32x4 v) {
    __builtin_nontemporal_store(v, (f32x4*)p);
}

// load 8 consecutive fp32 and round to bf16x8 (MFMA operand)
__device__ __forceinline__ bf16x8 cvt8(const float* __restrict__ p) {
    f32x4 a = *(const f32x4*)p;
    f32x4 b = *(const f32x4*)(p + 4);
    bf16x8 r;
    r[0] = (bf16)a[0]; r[1] = (bf16)a[1]; r[2] = (bf16)a[2]; r[3] = (bf16)a[3];
    r[4] = (bf16)b[0]; r[5] = (bf16)b[1]; r[6] = (bf16)b[2]; r[7] = (bf16)b[3];
    return r;
}
__device__ __forceinline__ bf16x8 cvt8v(f32x4 a, f32x4 b) {
    bf16x8 r;
    r[0] = (bf16)a[0]; r[1] = (bf16)a[1]; r[2] = (bf16)a[2]; r[3] = (bf16)a[3];
    r[4] = (bf16)b[0]; r[5] = (bf16)b[1]; r[6] = (bf16)b[2]; r[7] = (bf16)b[3];
    return r;
}

// ---- DPP 16-lane all-reduce sum on the VALU pipe ----
template <int CTRL>
__device__ __forceinline__ float dpp_add(float v) {
    int t = __builtin_amdgcn_update_dpp(0, __float_as_int(v), CTRL, 0xF, 0xF, false);
    return v + __int_as_float(t);
}
__device__ __forceinline__ float sum16(float v) {
    v = dpp_add<0x121>(v);  // row_ror:1
    v = dpp_add<0x122>(v);  // row_ror:2
    v = dpp_add<0x124>(v);  // row_ror:4
    v = dpp_add<0x128>(v);  // row_ror:8
    return v;
}

// ws layout (bytes):
//   [0,    8192)  Wf  bf16[64][64]  = W_mlp[:,0:64] @ W_init
//   [8192, 8320)  waf bf16[64]      = w_alpha[0:64] @ W_init
//   [8320, 8576)  bMf f32[64]       = b_mlp + W_mlp[:,0:64] @ b_init
//   [8576, 8580)  bAf f32[1]        = b_alpha + w_alpha[0:64] . b_init
// bf16 node cache lives in the TAIL of `out` (rebuilt every launch).
#define WS_WAF  8192
#define WS_BMF  8320
#define WS_BAF  8576

__global__ void prep_kernel(const float* __restrict__ W_init,
                            const float* __restrict__ b_init,
                            const float* __restrict__ W_mlp,
                            const float* __restrict__ b_mlp,
                            const float* __restrict__ W_alpha,
                            const float* __restrict__ b_alpha,
                            const float* __restrict__ node_fts,
                            char* __restrict__ ws,
                            bf16* __restrict__ ncache,
                            int nchunks)
{
    const int idx = blockIdx.x * 256 + threadIdx.x;
    if (blockIdx.x < 17) {
        bf16*  Wf  = (bf16*)ws;
        bf16*  waf = (bf16*)(ws + WS_WAF);
        float* bMf = (float*)(ws + WS_BMF);
        float* bAf = (float*)(ws + WS_BAF);
        if (idx < 4096) {
            const int o = idx >> 6, k = idx & 63;
            float acc = 0.f;
            for (int j = 0; j < 64; ++j)
                acc += W_mlp[o * 192 + j] * W_init[j * 64 + k];
            Wf[o * 64 + k] = (bf16)acc;
        } else if (idx < 4160) {
            const int o = idx - 4096;
            float acc = b_mlp[o];
            for (int j = 0; j < 64; ++j)
                acc += W_mlp[o * 192 + j] * b_init[j];
            bMf[o] = acc;
        } else if (idx < 4224) {
            const int k = idx - 4160;
            float acc = 0.f;
            for (int j = 0; j < 64; ++j)
                acc += W_alpha[j] * W_init[j * 64 + k];
            waf[k] = (bf16)acc;
        } else if (idx == 4224) {
            float acc = b_alpha[0];
            for (int j = 0; j < 64; ++j)
                acc += W_alpha[j] * b_init[j];
            bAf[0] = acc;
        }
    } else {
        // node feature cache: fp32 -> bf16 (identical rounding to the old
        // gather path), 8 floats per chunk
        const int i = idx - 17 * 256;
        if (i < nchunks) {
            f32x4 a = ldnt4(node_fts + (size_t)i * 8);
            f32x4 b = ldnt4(node_fts + (size_t)i * 8 + 4);
            *(bf16x8*)(ncache + (size_t)i * 8) = cvt8v(a, b);
        }
    }
}

// issue all global loads for one group into the (named) stage registers
#define ISSUE_STAGE(gs, hh, tt)                                               \
    {                                                                         \
        const float* ep_ = edge_fts + (((size_t)(gs) << 4) + n) * 64;         \
        efS0 = ldnt4(ep_ + q * 8);                                            \
        efS1 = ldnt4(ep_ + q * 8 + 4);                                        \
        efS2 = ldnt4(ep_ + 32 + q * 8);                                       \
        efS3 = ldnt4(ep_ + 32 + q * 8 + 4);                                   \
        if constexpr (NB) {                                                   \
            const bf16* hp_ = nc + (size_t)(hh) * 64;                         \
            const bf16* tp_ = nc + (size_t)(tt) * 64;                         \
            nhS0 = *(const bf16x8*)(hp_ + q * 8);                             \
            nhS1 = *(const bf16x8*)(hp_ + 32 + q * 8);                        \
            ntS0 = *(const bf16x8*)(tp_ + q * 8);                             \
            ntS1 = *(const bf16x8*)(tp_ + 32 + q * 8);                        \
        } else {                                                              \
            const float* hp_ = node_fts + (size_t)(hh) * 64;                  \
            const float* tp_ = node_fts + (size_t)(tt) * 64;                  \
            nhF0 = *(const f32x4*)(hp_ + q * 8);                              \
            nhF1 = *(const f32x4*)(hp_ + q * 8 + 4);                          \
            nhF2 = *(const f32x4*)(hp_ + 32 + q * 8);                         \
            nhF3 = *(const f32x4*)(hp_ + 32 + q * 8 + 4);                     \
            ntF0 = *(const f32x4*)(tp_ + q * 8);                              \
            ntF1 = *(const f32x4*)(tp_ + q * 8 + 4);                          \
            ntF2 = *(const f32x4*)(tp_ + 32 + q * 8);                         \
            ntF3 = *(const f32x4*)(tp_ + 32 + q * 8 + 4);                     \
        }                                                                     \
    }

// One wave = 16 edges, groups [g0, g1) grid-strided, 1-deep SW pipeline:
// consume stage(g) -> issue stage(g+S) with idx prefetched 2 iters ahead
// -> issue idx(g+2S) -> compute g. Stage loads are always OLDER than the
// idx loads, so consuming the stage never drains the idx prefetch.
template <bool NB>
__global__ __launch_bounds__(256, 3)
void edge_update_kernel(const float* __restrict__ node_fts,
                        const float* __restrict__ edge_fts,
                        const int*   __restrict__ edges,
                        const float* __restrict__ W_init,
                        const float* __restrict__ b_init,
                        const float* __restrict__ W_mlp,
                        const float* __restrict__ W_alpha,
                        const char*  __restrict__ ws,
                        const bf16*  __restrict__ nc,
                        float* __restrict__ out,
                        int E, int g0, int g1)
{
    __shared__ bf16  sW2[64][200];   // [out][k=192] 0..63 = Wf, 64..191 = W_mlp
    __shared__ bf16  sWa[224];       // 0..63 = waf, 64..191 = W_alpha
    __shared__ float sOut[4][1024];  // per-wave store bounce (16 rows x 64 cols)

    const int tid  = threadIdx.x;
    const int lane = tid & 63;
    const int wv   = tid >> 6;
    const int n    = lane & 15;   // MFMA col n / A-row m
    const int q    = lane >> 4;   // quad

    const bf16*  Wf  = (const bf16*)ws;
    const bf16*  waf = (const bf16*)(ws + WS_WAF);
    const float* bMf = (const float*)(ws + WS_BMF);
    const float* bAf = (const float*)(ws + WS_BAF);

    // ---- stage fused W2 + wa into LDS as bf16 ----
    for (int c = tid; c < 64 * 24; c += 256) {
        const int r = c / 24;
        const int o = (c - r * 24) * 8;
        if (o < 64) *(bf16x8*)(&sW2[r][o]) = *(const bf16x8*)(Wf + r * 64 + o);
        else        *(bf16x8*)(&sW2[r][o]) = cvt8(W_mlp + r * 192 + o);
    }
    if (tid < 24) {
        const int o = tid * 8;
        if (o < 64) *(bf16x8*)(&sWa[o]) = *(const bf16x8*)(waf + o);
        else        *(bf16x8*)(&sWa[o]) = cvt8(W_alpha + o);
    }
    __syncthreads();

    // ---- W_init B-frags in registers: B[k][col] = W_init[col][k] ----
    bf16x8 B1[2][4];
    UNROLL
    for (int kk = 0; kk < 2; ++kk)
        UNROLL
        for (int t = 0; t < 4; ++t)
            B1[kk][t] = cvt8(W_init + (t * 16 + n) * 64 + kk * 32 + q * 8);

    float bI[4], bM[4];
    UNROLL
    for (int t = 0; t < 4; ++t) {
        bI[t] = b_init[t * 16 + n];
        bM[t] = bMf[t * 16 + n];
    }
    const float bA = bAf[0];

    const int gStep = gridDim.x * 4;
    int g = g0 + blockIdx.x * 4 + wv;
    if (g >= g1) return;

    // named stage registers (statically allocated, no arrays -> no scratch)
    f32x4  efS0, efS1, efS2, efS3;
    bf16x8 nhS0, nhS1, ntS0, ntS1;
    f32x4  nhF0, nhF1, nhF2, nhF3, ntF0, ntF1, ntF2, ntF3;

    // ---- prologue: idx + stage for g; idx prefetch for g+S ----
    {
        const int h0 = ldnti(edges + ((size_t)g << 4) + n);
        const int t0 = ldnti(edges + E + ((size_t)g << 4) + n);
        ISSUE_STAGE(g, h0, t0);
    }
    int gl = (g + gStep < g1) ? g + gStep : g;
    int hn = ldnti(edges + ((size_t)gl << 4) + n);
    int tn = ldnti(edges + E + ((size_t)gl << 4) + n);

    float* const ob = &sOut[wv][0];

    for (;;) {
        // ---- consume stage (compiler waits only the stage loads) ----
        bf16x8 A[6];
        A[0] = cvt8v(efS0, efS1);
        A[1] = cvt8v(efS2, efS3);
        if constexpr (NB) {
            A[2] = nhS0; A[3] = nhS1;
            A[4] = ntS0; A[5] = ntS1;
        } else {
            A[2] = cvt8v(nhF0, nhF1); A[3] = cvt8v(nhF2, nhF3);
            A[4] = cvt8v(ntF0, ntF1); A[5] = cvt8v(ntF2, ntF3);
        }

        // ---- issue next stage + next-next idx ----
        const bool haveNext = (g + gStep) < g1;
        const int  gs = haveNext ? g + gStep : g;
        ISSUE_STAGE(gs, hn, tn);
        {
            const int g2  = gs + gStep;
            const int g2l = (g2 < g1) ? g2 : gs;
            hn = ldnti(edges + ((size_t)g2l << 4) + n);
            tn = ldnti(edges + E + ((size_t)g2l << 4) + n);
        }

        // ---- GEMM-R: e (residual) in C-layout ----
        f32x4 accE[4] = { f32x4{0,0,0,0}, f32x4{0,0,0,0}, f32x4{0,0,0,0}, f32x4{0,0,0,0} };
        UNROLL
        for (int kk = 0; kk < 2; ++kk)
            UNROLL
            for (int t = 0; t < 4; ++t) accE[t] = MFMA16(A[kk], B1[kk][t], accE[t]);

        // ---- GEMM2: K=192, 4 N-tiles + broadcast alpha column ----
        f32x4 accP[4] = { f32x4{0,0,0,0}, f32x4{0,0,0,0}, f32x4{0,0,0,0}, f32x4{0,0,0,0} };
        f32x4 accA = f32x4{0,0,0,0};
        UNROLL
        for (int kk = 0; kk < 6; ++kk) {
            accA = MFMA16(A[kk], *(const bf16x8*)(&sWa[kk * 32 + q * 8]), accA);
            UNROLL
            for (int t = 0; t < 4; ++t)
                accP[t] = MFMA16(A[kk], *(const bf16x8*)(&sW2[t * 16 + n][kk * 32 + q * 8]), accP[t]);
        }

        // ---- epilogue: lane holds rows q*4+r, cols t*16+n ----
        float eF[4][4], pv[4][4], alpha[4];
        UNROLL
        for (int t = 0; t < 4; ++t)
            UNROLL
            for (int r = 0; r < 4; ++r) eF[t][r] = accE[t][r] + bI[t];
        UNROLL
        for (int r = 0; r < 4; ++r) alpha[r] = fast_sigmoid(accA[r] + bA);
        UNROLL
        for (int t = 0; t < 4; ++t)
            UNROLL
            for (int r = 0; r < 4; ++r) pv[t][r] = fast_tanh(accP[t][r] + bM[t]);

        // LN1
        float s1[4], s2[4];
        UNROLL
        for (int r = 0; r < 4; ++r) {
            s1[r] = pv[0][r] + pv[1][r] + pv[2][r] + pv[3][r];
            s2[r] = pv[0][r]*pv[0][r] + pv[1][r]*pv[1][r] + pv[2][r]*pv[2][r] + pv[3][r]*pv[3][r];
        }
        UNROLL
        for (int r = 0; r < 4; ++r) { s1[r] = sum16(s1[r]); s2[r] = sum16(s2[r]); }

        float o2[4][4];
        UNROLL
        for (int r = 0; r < 4; ++r) {
            const float mean = s1[r] * 0.015625f;
            const float var  = fmaxf(s2[r] * 0.015625f - mean * mean, 0.0f);
            const float rs   = fast_rsq(var + 1e-5f);
            UNROLL
            for (int t = 0; t < 4; ++t)
                o2[t][r] = eF[t][r] + (pv[t][r] - mean) * rs * alpha[r];
        }

        // LN2
        UNROLL
        for (int r = 0; r < 4; ++r) {
            s1[r] = o2[0][r] + o2[1][r] + o2[2][r] + o2[3][r];
            s2[r] = o2[0][r]*o2[0][r] + o2[1][r]*o2[1][r] + o2[2][r]*o2[2][r] + o2[3][r]*o2[3][r];
        }
        UNROLL
        for (int r = 0; r < 4; ++r) { s1[r] = sum16(s1[r]); s2[r] = sum16(s2[r]); }

        // ---- store via per-wave LDS bounce -> 4x NT dwordx4 (full lines) ----
        UNROLL
        for (int r = 0; r < 4; ++r) {
            const float mean = s1[r] * 0.015625f;
            const float var  = fmaxf(s2[r] * 0.015625f - mean * mean, 0.0f);
            const float rs   = fast_rsq(var + 1e-5f);
            UNROLL
            for (int t = 0; t < 4; ++t)
                ob[(q * 4 + r) * 64 + t * 16 + n] = (o2[t][r] - mean) * rs;
        }
        {
            float* op = out + (((size_t)g << 4)) * 64;
            UNROLL
            for (int j = 0; j < 4; ++j)
                stnt4(op + j * 256 + lane * 4, *(const f32x4*)(ob + j * 256 + lane * 4));
        }

        if (!haveNext) return;
        g += gStep;
    }
}

extern "C" void kernel_launch(void* const* d_in, const int* in_sizes, int n_in,
                              void* d_out, int out_size, void* d_ws, size_t ws_size,
                              hipStream_t stream) {
    const float* node_fts = (const float*)d_in[0];
    const float* edge_fts = (const float*)d_in[1];
    const int*   edges    = (const int*)d_in[2];
    const float* W_init   = (const float*)d_in[3];
    const float* b_init   = (const float*)d_in[4];
    const float* W_mlp    = (const float*)d_in[5];
    const float* b_mlp    = (const float*)d_in[6];
    const float* W_alpha  = (const float*)d_in[7];
    const float* b_alpha  = (const float*)d_in[8];
    float* out = (float*)d_out;
    char*  ws  = (char*)d_ws;

    const int E = in_sizes[2] / 2;       // edges is [2, E]
    const int N = in_sizes[0] / 64;      // node_fts is [N, 64]
    const int totalGroups = E >> 4;

    // bf16 node cache in the TAIL of `out`: rows of the last cacheRows edges.
    int cacheRows = ((N + 1) / 2 + 15) & ~15;
    cacheRows += (E - cacheRows) & 15;
    const bool useCache = (E >= cacheRows + 16) && (cacheRows > 0);

    bf16* ncache = useCache ? (bf16*)(out + (size_t)(E - cacheRows) * 64) : (bf16*)nullptr;
    const int nchunks = useCache ? N * 8 : 0;

    const int prep_blocks = 17 + (nchunks + 255) / 256;
    hipLaunchKernelGGL(prep_kernel, dim3(prep_blocks), dim3(256), 0, stream,
                       W_init, b_init, W_mlp, b_mlp, W_alpha, b_alpha,
                       node_fts, ws, ncache, nchunks);

    if (useCache) {
        const int mainGroups = (E - cacheRows) >> 4;
        // main: bf16 gathers from the out-tail cache
        hipLaunchKernelGGL((edge_update_kernel<true>), dim3(2048), dim3(256), 0, stream,
                           node_fts, edge_fts, edges, W_init, b_init,
                           W_mlp, W_alpha, ws, ncache, out, E, 0, mainGroups);
        // tail: fp32 gathers; overwrites the cache region with real outputs.
        hipLaunchKernelGGL((edge_update_kernel<false>), dim3(2048), dim3(256), 0, stream,
                           node_fts, edge_fts, edges, W_init, b_init,
                           W_mlp, W_alpha, ws, (const bf16*)nullptr, out, E,
                           mainGroups, totalGroups);
    } else {
        hipLaunchKernelGGL((edge_update_kernel<false>), dim3(2048), dim3(256), 0, stream,
                           node_fts, edge_fts, edges, W_init, b_init,
                           W_mlp, W_alpha, ws, (const bf16*)nullptr, out, E,
                           0, totalGroups);
    }
}

// Round 5
// 700.998 us; speedup vs baseline: 1.0475x; 1.0475x over previous
//
#include <hip/hip_runtime.h>
#include <hip/hip_bf16.h>

typedef __bf16 bf16;
typedef bf16 bf16x8 __attribute__((ext_vector_type(8)));
typedef float f32x4 __attribute__((ext_vector_type(4)));

#define MFMA16(a, b, c) __builtin_amdgcn_mfma_f32_16x16x32_bf16((a), (b), (c), 0, 0, 0)
#define UNROLL _Pragma("unroll")

__device__ __forceinline__ float fast_rcp(float x) { return __builtin_amdgcn_rcpf(x); }
__device__ __forceinline__ float fast_rsq(float x) { return __builtin_amdgcn_rsqf(x); }
__device__ __forceinline__ float fast_tanh(float x) {
    float e = __expf(2.0f * x);
    return 1.0f - 2.0f * fast_rcp(e + 1.0f);
}
__device__ __forceinline__ float fast_sigmoid(float x) {
    return fast_rcp(1.0f + __expf(-x));
}

// NT loads for single-use streams (edge_fts): keeps them out of L2/L3 so the
// node table stays resident. NT *stores* are NOT used: round-4 evidence
// showed they bypass L2 write-combining -> sub-line RMW (+144MB FETCH).
__device__ __forceinline__ f32x4 ldnt4(const float* __restrict__ p) {
    return __builtin_nontemporal_load((const f32x4*)p);
}

// load 8 consecutive fp32 and round to bf16x8 (MFMA operand)
__device__ __forceinline__ bf16x8 cvt8(const float* __restrict__ p) {
    f32x4 a = *(const f32x4*)p;
    f32x4 b = *(const f32x4*)(p + 4);
    bf16x8 r;
    r[0] = (bf16)a[0]; r[1] = (bf16)a[1]; r[2] = (bf16)a[2]; r[3] = (bf16)a[3];
    r[4] = (bf16)b[0]; r[5] = (bf16)b[1]; r[6] = (bf16)b[2]; r[7] = (bf16)b[3];
    return r;
}
__device__ __forceinline__ bf16x8 cvt8v(f32x4 a, f32x4 b) {
    bf16x8 r;
    r[0] = (bf16)a[0]; r[1] = (bf16)a[1]; r[2] = (bf16)a[2]; r[3] = (bf16)a[3];
    r[4] = (bf16)b[0]; r[5] = (bf16)b[1]; r[6] = (bf16)b[2]; r[7] = (bf16)b[3];
    return r;
}

// ---- DPP 16-lane all-reduce sum on the VALU pipe ----
template <int CTRL>
__device__ __forceinline__ float dpp_add(float v) {
    int t = __builtin_amdgcn_update_dpp(0, __float_as_int(v), CTRL, 0xF, 0xF, false);
    return v + __int_as_float(t);
}
__device__ __forceinline__ float sum16(float v) {
    v = dpp_add<0x121>(v);  // row_ror:1
    v = dpp_add<0x122>(v);  // row_ror:2
    v = dpp_add<0x124>(v);  // row_ror:4
    v = dpp_add<0x128>(v);  // row_ror:8
    return v;
}

// ws layout (bytes):
//   [0,    8192)  Wf  bf16[64][64]  = W_mlp[:,0:64] @ W_init
//   [8192, 8320)  waf bf16[64]      = w_alpha[0:64] @ W_init
//   [8320, 8576)  bMf f32[64]       = b_mlp + W_mlp[:,0:64] @ b_init
//   [8576, 8580)  bAf f32[1]        = b_alpha + w_alpha[0:64] . b_init
// bf16 node cache lives in the TAIL of `out` (rebuilt every launch).
#define WS_WAF  8192
#define WS_BMF  8320
#define WS_BAF  8576

__global__ void prep_kernel(const float* __restrict__ W_init,
                            const float* __restrict__ b_init,
                            const float* __restrict__ W_mlp,
                            const float* __restrict__ b_mlp,
                            const float* __restrict__ W_alpha,
                            const float* __restrict__ b_alpha,
                            const float* __restrict__ node_fts,
                            char* __restrict__ ws,
                            bf16* __restrict__ ncache,
                            int nchunks)
{
    const int idx = blockIdx.x * 256 + threadIdx.x;
    if (blockIdx.x < 17) {
        bf16*  Wf  = (bf16*)ws;
        bf16*  waf = (bf16*)(ws + WS_WAF);
        float* bMf = (float*)(ws + WS_BMF);
        float* bAf = (float*)(ws + WS_BAF);
        if (idx < 4096) {
            const int o = idx >> 6, k = idx & 63;
            float acc = 0.f;
            for (int j = 0; j < 64; ++j)
                acc += W_mlp[o * 192 + j] * W_init[j * 64 + k];
            Wf[o * 64 + k] = (bf16)acc;
        } else if (idx < 4160) {
            const int o = idx - 4096;
            float acc = b_mlp[o];
            for (int j = 0; j < 64; ++j)
                acc += W_mlp[o * 192 + j] * b_init[j];
            bMf[o] = acc;
        } else if (idx < 4224) {
            const int k = idx - 4160;
            float acc = 0.f;
            for (int j = 0; j < 64; ++j)
                acc += W_alpha[j] * W_init[j * 64 + k];
            waf[k] = (bf16)acc;
        } else if (idx == 4224) {
            float acc = b_alpha[0];
            for (int j = 0; j < 64; ++j)
                acc += W_alpha[j] * b_init[j];
            bAf[0] = acc;
        }
    } else {
        // node feature cache: fp32 -> bf16 (identical rounding to the old
        // gather path), 8 floats per chunk; cached stores keep it warm in L2.
        const int i = idx - 17 * 256;
        if (i < nchunks) {
            f32x4 a = ldnt4(node_fts + (size_t)i * 8);
            f32x4 b = ldnt4(node_fts + (size_t)i * 8 + 4);
            *(bf16x8*)(ncache + (size_t)i * 8) = cvt8v(a, b);
        }
    }
}

// One wave = 16 edges, groups [g0, g1) grid-strided.
// NB=true: gather nodes from the bf16 cache (1 line per endpoint).
// NB=false: gather fp32 node_fts directly (tail / fallback).
template <bool NB>
__global__ __launch_bounds__(256, 3)
void edge_update_kernel(const float* __restrict__ node_fts,
                        const float* __restrict__ edge_fts,
                        const int*   __restrict__ edges,
                        const float* __restrict__ W_init,
                        const float* __restrict__ b_init,
                        const float* __restrict__ W_mlp,
                        const float* __restrict__ W_alpha,
                        const char*  __restrict__ ws,
                        const bf16*  __restrict__ nc,
                        float* __restrict__ out,
                        int E, int g0, int g1)
{
    __shared__ bf16  sW2[64][200];   // [out][k=192] 0..63 = Wf, 64..191 = W_mlp
    __shared__ bf16  sWa[224];       // 0..63 = waf, 64..191 = W_alpha
    __shared__ float sOut[4][1024];  // per-wave store bounce (16 rows x 64 cols)

    const int tid  = threadIdx.x;
    const int lane = tid & 63;
    const int wv   = tid >> 6;
    const int n    = lane & 15;   // MFMA col n / A-row m
    const int q    = lane >> 4;   // quad

    const bf16*  Wf  = (const bf16*)ws;
    const bf16*  waf = (const bf16*)(ws + WS_WAF);
    const float* bMf = (const float*)(ws + WS_BMF);
    const float* bAf = (const float*)(ws + WS_BAF);

    // ---- stage fused W2 + wa into LDS as bf16 ----
    for (int c = tid; c < 64 * 24; c += 256) {
        const int r = c / 24;
        const int o = (c - r * 24) * 8;
        if (o < 64) *(bf16x8*)(&sW2[r][o]) = *(const bf16x8*)(Wf + r * 64 + o);
        else        *(bf16x8*)(&sW2[r][o]) = cvt8(W_mlp + r * 192 + o);
    }
    if (tid < 24) {
        const int o = tid * 8;
        if (o < 64) *(bf16x8*)(&sWa[o]) = *(const bf16x8*)(waf + o);
        else        *(bf16x8*)(&sWa[o]) = cvt8(W_alpha + o);
    }
    __syncthreads();

    // ---- W_init B-frags in registers: B[k][col] = W_init[col][k] ----
    bf16x8 B1[2][4];
    UNROLL
    for (int kk = 0; kk < 2; ++kk)
        UNROLL
        for (int t = 0; t < 4; ++t)
            B1[kk][t] = cvt8(W_init + (t * 16 + n) * 64 + kk * 32 + q * 8);

    float bI[4], bM[4];
    UNROLL
    for (int t = 0; t < 4; ++t) {
        bI[t] = b_init[t * 16 + n];
        bM[t] = bMf[t * 16 + n];
    }
    const float bA = bAf[0];

    float* const ob = &sOut[wv][0];

    for (int g = g0 + blockIdx.x * 4 + wv; g < g1; g += gridDim.x * 4) {
        const int e0 = g << 4;
        const int h  = edges[e0 + n];
        const int tl = edges[E + e0 + n];

        // A-fragments: lane's A-row m = n; k = seg*32 + q*8 + j
        bf16x8 A[6];
        const float* ep = edge_fts + (size_t)(e0 + n) * 64;
        A[0] = cvt8v(ldnt4(ep + q * 8), ldnt4(ep + q * 8 + 4));
        A[1] = cvt8v(ldnt4(ep + 32 + q * 8), ldnt4(ep + 32 + q * 8 + 4));
        if constexpr (NB) {
            const bf16* hp = nc + (size_t)h * 64;
            const bf16* tp = nc + (size_t)tl * 64;
            A[2] = *(const bf16x8*)(hp + q * 8);
            A[3] = *(const bf16x8*)(hp + 32 + q * 8);
            A[4] = *(const bf16x8*)(tp + q * 8);
            A[5] = *(const bf16x8*)(tp + 32 + q * 8);
        } else {
            const float* hp = node_fts + (size_t)h * 64;
            const float* tp = node_fts + (size_t)tl * 64;
            A[2] = cvt8(hp + q * 8);
            A[3] = cvt8(hp + 32 + q * 8);
            A[4] = cvt8(tp + q * 8);
            A[5] = cvt8(tp + 32 + q * 8);
        }

        // ---- GEMM-R: e (residual) in C-layout ----
        f32x4 accE[4] = { f32x4{0,0,0,0}, f32x4{0,0,0,0}, f32x4{0,0,0,0}, f32x4{0,0,0,0} };
        UNROLL
        for (int kk = 0; kk < 2; ++kk)
            UNROLL
            for (int t = 0; t < 4; ++t) accE[t] = MFMA16(A[kk], B1[kk][t], accE[t]);

        // ---- GEMM2: K=192, 4 N-tiles + broadcast alpha column ----
        f32x4 accP[4] = { f32x4{0,0,0,0}, f32x4{0,0,0,0}, f32x4{0,0,0,0}, f32x4{0,0,0,0} };
        f32x4 accA = f32x4{0,0,0,0};
        UNROLL
        for (int kk = 0; kk < 6; ++kk) {
            accA = MFMA16(A[kk], *(const bf16x8*)(&sWa[kk * 32 + q * 8]), accA);
            UNROLL
            for (int t = 0; t < 4; ++t)
                accP[t] = MFMA16(A[kk], *(const bf16x8*)(&sW2[t * 16 + n][kk * 32 + q * 8]), accP[t]);
        }

        // ---- epilogue: lane holds rows q*4+r, cols t*16+n ----
        float eF[4][4], pv[4][4], alpha[4];
        UNROLL
        for (int t = 0; t < 4; ++t)
            UNROLL
            for (int r = 0; r < 4; ++r) eF[t][r] = accE[t][r] + bI[t];
        UNROLL
        for (int r = 0; r < 4; ++r) alpha[r] = fast_sigmoid(accA[r] + bA);
        UNROLL
        for (int t = 0; t < 4; ++t)
            UNROLL
            for (int r = 0; r < 4; ++r) pv[t][r] = fast_tanh(accP[t][r] + bM[t]);

        // LN1 over 64 cols: per-lane partials + DPP all-reduce over 16 n-lanes
        float s1[4], s2[4];
        UNROLL
        for (int r = 0; r < 4; ++r) {
            s1[r] = pv[0][r] + pv[1][r] + pv[2][r] + pv[3][r];
            s2[r] = pv[0][r]*pv[0][r] + pv[1][r]*pv[1][r] + pv[2][r]*pv[2][r] + pv[3][r]*pv[3][r];
        }
        UNROLL
        for (int r = 0; r < 4; ++r) { s1[r] = sum16(s1[r]); s2[r] = sum16(s2[r]); }

        float o2[4][4];
        UNROLL
        for (int r = 0; r < 4; ++r) {
            const float mean = s1[r] * 0.015625f;
            const float var  = fmaxf(s2[r] * 0.015625f - mean * mean, 0.0f);
            const float rs   = fast_rsq(var + 1e-5f);
            UNROLL
            for (int t = 0; t < 4; ++t)
                o2[t][r] = eF[t][r] + (pv[t][r] - mean) * rs * alpha[r];
        }

        // LN2
        UNROLL
        for (int r = 0; r < 4; ++r) {
            s1[r] = o2[0][r] + o2[1][r] + o2[2][r] + o2[3][r];
            s2[r] = o2[0][r]*o2[0][r] + o2[1][r]*o2[1][r] + o2[2][r]*o2[2][r] + o2[3][r]*o2[3][r];
        }
        UNROLL
        for (int r = 0; r < 4; ++r) { s1[r] = sum16(s1[r]); s2[r] = sum16(s2[r]); }

        // ---- store via per-wave LDS bounce -> 4x cached dwordx4 (full lines,
        // L2 write-combining merges to whole 128B lines) ----
        UNROLL
        for (int r = 0; r < 4; ++r) {
            const float mean = s1[r] * 0.015625f;
            const float var  = fmaxf(s2[r] * 0.015625f - mean * mean, 0.0f);
            const float rs   = fast_rsq(var + 1e-5f);
            UNROLL
            for (int t = 0; t < 4; ++t)
                ob[(q * 4 + r) * 64 + t * 16 + n] = (o2[t][r] - mean) * rs;
        }
        {
            float* op = out + ((size_t)e0) * 64;
            UNROLL
            for (int j = 0; j < 4; ++j)
                *(f32x4*)(op + j * 256 + lane * 4) = *(const f32x4*)(ob + j * 256 + lane * 4);
        }
    }
}

extern "C" void kernel_launch(void* const* d_in, const int* in_sizes, int n_in,
                              void* d_out, int out_size, void* d_ws, size_t ws_size,
                              hipStream_t stream) {
    const float* node_fts = (const float*)d_in[0];
    const float* edge_fts = (const float*)d_in[1];
    const int*   edges    = (const int*)d_in[2];
    const float* W_init   = (const float*)d_in[3];
    const float* b_init   = (const float*)d_in[4];
    const float* W_mlp    = (const float*)d_in[5];
    const float* b_mlp    = (const float*)d_in[6];
    const float* W_alpha  = (const float*)d_in[7];
    const float* b_alpha  = (const float*)d_in[8];
    float* out = (float*)d_out;
    char*  ws  = (char*)d_ws;

    const int E = in_sizes[2] / 2;       // edges is [2, E]
    const int N = in_sizes[0] / 64;      // node_fts is [N, 64]
    const int totalGroups = E >> 4;

    // bf16 node cache in the TAIL of `out`: rows of the last cacheRows edges.
    int cacheRows = ((N + 1) / 2 + 15) & ~15;
    cacheRows += (E - cacheRows) & 15;
    const bool useCache = (E >= cacheRows + 16) && (cacheRows > 0);

    bf16* ncache = useCache ? (bf16*)(out + (size_t)(E - cacheRows) * 64) : (bf16*)nullptr;
    const int nchunks = useCache ? N * 8 : 0;

    const int prep_blocks = 17 + (nchunks + 255) / 256;
    hipLaunchKernelGGL(prep_kernel, dim3(prep_blocks), dim3(256), 0, stream,
                       W_init, b_init, W_mlp, b_mlp, W_alpha, b_alpha,
                       node_fts, ws, ncache, nchunks);

    if (useCache) {
        const int mainGroups = (E - cacheRows) >> 4;
        // main: bf16 gathers from the out-tail cache
        hipLaunchKernelGGL((edge_update_kernel<true>), dim3(2048), dim3(256), 0, stream,
                           node_fts, edge_fts, edges, W_init, b_init,
                           W_mlp, W_alpha, ws, ncache, out, E, 0, mainGroups);
        // tail: fp32 gathers; overwrites the cache region with real outputs.
        hipLaunchKernelGGL((edge_update_kernel<false>), dim3(1024), dim3(256), 0, stream,
                           node_fts, edge_fts, edges, W_init, b_init,
                           W_mlp, W_alpha, ws, (const bf16*)nullptr, out, E,
                           mainGroups, totalGroups);
    } else {
        hipLaunchKernelGGL((edge_update_kernel<false>), dim3(2048), dim3(256), 0, stream,
                           node_fts, edge_fts, edges, W_init, b_init,
                           W_mlp, W_alpha, ws, (const bf16*)nullptr, out, E,
                           0, totalGroups);
    }
}